// Round 20
// baseline (122.192 us; speedup 1.0000x reference)
//
#include <hip/hip_runtime.h>

// VQ nearest-codebook via bf16 MFMA GEMM + exact-fp32 rescue.
// score(n,k) = 0.5*|e_k|^2 - z_n.e_k (monotone in squared distance)
//
// Round-20: 32x32x16 MFMA with FRAGMENT-ORDERED e-LDS (fixes r19's 4.19e6
// bank conflicts). gload_lds writes base+lane*16 linearly, so the per-lane
// GLOBAL source address is chosen to be each lane's A-fragment chunk:
// region r=(wc,ks,nt) of 1KB, lane l -> row=nt*32+(l&31), k=ks*16+(l>>5)*8.
// Inner-loop e-reads are lane-contiguous b128 -> conflict-free, zero
// address math. Everything else identical to r19 (maps verified correct).

typedef unsigned short ushort;
typedef unsigned int u32;
typedef __attribute__((ext_vector_type(8))) short short8;
typedef __attribute__((ext_vector_type(16))) float f32x16;

#define C 256
#define MTOK 16384
#define NCODE 8192
#define BM 256
#define BN 128
#define BK 64
#define TPB 512
#define NSLAB 128            // per-(nb,wc) entries, 64-code granularity
#define NTILE (C / BK)       // 4
// zf chunk order: [mb][wr 0..3][kstep 0..15][mt 0..1][lane 0..63], 16B each

__device__ __forceinline__ ushort bf16_rne(float x) {
    unsigned u = __float_as_uint(x);
    return (ushort)((u + 0x7FFFu + ((u >> 16) & 1u)) >> 16);
}

__device__ __forceinline__ bool lexlt(float as, int ai, float bs, int bi) {
    return as < bs || (as == bs && ai < bi);
}

// float sortable key: truncate score to 25 bits, OR in 7-bit local code id.
__device__ __forceinline__ float fkey(float sc, int id) {
    return __uint_as_float((__float_as_uint(sc) & 0xFFFFFF80u) | (u32)id);
}

__device__ __forceinline__ void ins2f(float& k1, float& k2, float key) {
    k2 = fminf(k2, fmaxf(k1, key));
    k1 = fminf(k1, key);
}

__device__ __forceinline__ void merge2f(float& k1, float& k2, float o1, float o2) {
    const float lo = fminf(k1, o1);
    const float hi = fmaxf(k1, o1);
    k2 = fminf(hi, fminf(k2, o2));
    k1 = lo;
}

__device__ __forceinline__ void gload_lds16(const ushort* g, ushort* l) {
    __builtin_amdgcn_global_load_lds(
        (const __attribute__((address_space(1))) unsigned int*)g,
        (__attribute__((address_space(3))) unsigned int*)l, 16, 0, 0);
}

// fused: emb -> bf16 cast + half-norms (one pass over emb)
__global__ __launch_bounds__(256) void vq_ecast(const float* __restrict__ emb,
                                                ushort* __restrict__ eb,
                                                float* __restrict__ hn) {
    typedef __attribute__((ext_vector_type(4))) ushort us4;
    const int lane = threadIdx.x & 63;
    const int wid = threadIdx.x >> 6;
    const int row0 = blockIdx.x * 16 + wid * 4;
    #pragma unroll
    for (int j = 0; j < 4; ++j) {
        const int k = row0 + j;
        const float4 v = *reinterpret_cast<const float4*>(
            emb + (size_t)k * C + lane * 4);
        us4 h;
        h[0] = bf16_rne(v.x);
        h[1] = bf16_rne(v.y);
        h[2] = bf16_rne(v.z);
        h[3] = bf16_rne(v.w);
        *reinterpret_cast<us4*>(eb + (size_t)k * C + lane * 4) = h;
        float s = v.x * v.x + v.y * v.y + v.z * v.z + v.w * v.w;
        #pragma unroll
        for (int off = 32; off; off >>= 1) s += __shfl_down(s, off);
        if (lane == 0) hn[k] = 0.5f * s;
    }
}

// z fp32 -> bf16 in 32x32x16 B-fragment order (one 16B chunk per thread)
__global__ __launch_bounds__(256) void vq_zfrag(const float* __restrict__ z,
                                                ushort* __restrict__ zf) {
    typedef __attribute__((ext_vector_type(8))) ushort us8;
    const int c = blockIdx.x * 256 + threadIdx.x;   // chunk id, 524288 total
    const int lane = c & 63;
    const int mt = (c >> 6) & 1;
    const int ks = (c >> 7) & 15;
    const int wr = (c >> 11) & 3;
    const int mb = c >> 13;
    const int row = mb * 256 + wr * 64 + mt * 32 + (lane & 31);   // token
    const int col = ks * 16 + (lane >> 5) * 8;                    // k
    const float4 v0 = *reinterpret_cast<const float4*>(z + (size_t)row * C + col);
    const float4 v1 = *reinterpret_cast<const float4*>(z + (size_t)row * C + col + 4);
    us8 o;
    o[0] = bf16_rne(v0.x); o[1] = bf16_rne(v0.y);
    o[2] = bf16_rne(v0.z); o[3] = bf16_rne(v0.w);
    o[4] = bf16_rne(v1.x); o[5] = bf16_rne(v1.y);
    o[6] = bf16_rne(v1.z); o[7] = bf16_rne(v1.w);
    *reinterpret_cast<us8*>(zf + (size_t)c * 8) = o;
}

__global__ __launch_bounds__(TPB) void vq_gemm(
    const ushort* __restrict__ zf, const ushort* __restrict__ eb,
    const float* __restrict__ hn, float2* __restrict__ slab) {
    __shared__ ushort smem[2 * BN * BK];   // 32 KB: e double-buffer

    const int tid = threadIdx.x;
    const int lane = tid & 63;
    const int wid = __builtin_amdgcn_readfirstlane(tid >> 6);
    const int wr = wid >> 1;          // 0..3 (M quarter, tokens)
    const int wc = wid & 1;           // 0..1 (N half, codes)
    const int mb = blockIdx.x;
    const int mbase = mb * BM;
    const int nb = blockIdx.y;
    const int nbase = nb * BN;

    // e staging in fragment order: 16 regions/tile of 1KB; region
    // r = i*8+wid = (swc<<3)|(sks<<1)|snt; lane l holds chunk
    // row = swc*64+snt*32+(l&31), k = sks*16+(l>>5)*8 (its A-fragment).
    const int lrow = lane & 31;
    const int lkh = (lane >> 5) * 8;

    // z fragment base for this wave (ushort units)
    const ushort* zbw = zf + ((size_t)(mb * 4 + wr) * 2048 + lane) * 8;

    f32x16 acc[2][2];
    #pragma unroll
    for (int a = 0; a < 2; ++a)
        #pragma unroll
        for (int b = 0; b < 2; ++b)
            #pragma unroll
            for (int e = 0; e < 16; ++e) acc[a][b][e] = 0.f;

    // prologue: stage e(0) into buf0
    #pragma unroll
    for (int i = 0; i < 2; ++i) {
        const int r = i * 8 + wid;
        const int swc = r >> 3, sks = (r >> 1) & 3, snt = r & 1;
        const int row = nbase + swc * 64 + snt * 32 + lrow;
        gload_lds16(eb + (size_t)row * C + sks * 16 + lkh, &smem[r * 512]);
    }
    __syncthreads();

    #pragma unroll 1
    for (int kk = 0; kk < NTILE; ++kk) {
        // stage e(kk+1) into the other buffer (flies during compute, 0 VGPR)
        if (kk + 1 < NTILE) {
            const int k0 = (kk + 1) * BK;
            ushort* Bn = &smem[((kk + 1) & 1) * BN * BK];
            #pragma unroll
            for (int i = 0; i < 2; ++i) {
                const int r = i * 8 + wid;
                const int swc = r >> 3, sks = (r >> 1) & 3, snt = r & 1;
                const int row = nbase + swc * 64 + snt * 32 + lrow;
                gload_lds16(eb + (size_t)row * C + k0 + sks * 16 + lkh,
                            &Bn[r * 512]);
            }
        }

        const ushort* Bt = &smem[(kk & 1) * BN * BK];
        #pragma unroll 1
        for (int ks = 0; ks < 4; ++ks) {
            short8 ea[2], zb2[2];
            #pragma unroll
            for (int mt = 0; mt < 2; ++mt)
                zb2[mt] = *reinterpret_cast<const short8*>(
                    zbw + ((kk * 4 + ks) * 2 + mt) * 512);
            #pragma unroll
            for (int nt = 0; nt < 2; ++nt)
                ea[nt] = *reinterpret_cast<const short8*>(
                    &Bt[(wc * 8 + ks * 2 + nt) * 512 + lane * 8]);
            // A = e (codes = M), B = z (tokens = N) -> D col = token
            #pragma unroll
            for (int mt = 0; mt < 2; ++mt)
                #pragma unroll
                for (int nt = 0; nt < 2; ++nt)
                    acc[mt][nt] = __builtin_amdgcn_mfma_f32_32x32x16_bf16(
                        ea[nt], zb2[mt], acc[mt][nt], 0, 0, 0);
        }
        __syncthreads();   // buf reads done + next e resident
    }

    // ---- epilogue: per-token (in-lane) top-2 over this wave's 64 codes ----
    // D: col = token = mt*32 + (lane&31); row-code = nt*32 + r + 8q + 4*(lane>>5)
    const int hb = 4 * (lane >> 5);
    float4 hv[2][4];
    #pragma unroll
    for (int nt = 0; nt < 2; ++nt)
        #pragma unroll
        for (int q = 0; q < 4; ++q)
            hv[nt][q] = *reinterpret_cast<const float4*>(
                &hn[nbase + wc * 64 + nt * 32 + q * 8 + hb]);

    #pragma unroll
    for (int mt = 0; mt < 2; ++mt) {
        float k1 = 3.4e38f, k2 = 3.4e38f;
        #pragma unroll
        for (int nt = 0; nt < 2; ++nt) {
            #pragma unroll
            for (int q = 0; q < 4; ++q) {
                const int bid = wc * 64 + nt * 32 + q * 8 + hb;
                ins2f(k1, k2, fkey(hv[nt][q].x - acc[mt][nt][q * 4 + 0], bid | 0));
                ins2f(k1, k2, fkey(hv[nt][q].y - acc[mt][nt][q * 4 + 1], bid | 1));
                ins2f(k1, k2, fkey(hv[nt][q].z - acc[mt][nt][q * 4 + 2], bid | 2));
                ins2f(k1, k2, fkey(hv[nt][q].w - acc[mt][nt][q * 4 + 3], bid | 3));
            }
        }
        merge2f(k1, k2, __shfl_xor(k1, 32), __shfl_xor(k2, 32));
        if (lane < 32) {
            const int token = mbase + wr * 64 + mt * 32 + lane;
            slab[(size_t)token * NSLAB + nb * 2 + wc] = make_float2(k1, k2);
        }
    }
}

__global__ __launch_bounds__(256) void vq_pick(
    const float* __restrict__ z, const float* __restrict__ emb,
    const float2* __restrict__ slab, float* __restrict__ out) {
    const int token = blockIdx.x * 4 + (threadIdx.x >> 6);
    const int lane = threadIdx.x & 63;

    // two entries per lane, same nbase (nb = lane) -> key-level merge valid
    const float2 e0 = slab[(size_t)token * NSLAB + 2 * lane];
    const float2 e1 = slab[(size_t)token * NSLAB + 2 * lane + 1];
    float k1 = e0.x, k2 = e0.y;
    merge2f(k1, k2, e1.x, e1.y);
    const u32 u1 = __float_as_uint(k1);
    const u32 u2 = __float_as_uint(k2);
    const float cs1 = __uint_as_float(u1 & 0xFFFFFF80u);
    const float cs2 = __uint_as_float(u2 & 0xFFFFFF80u);
    const int ci1 = lane * 128 + (int)(u1 & 0x7Fu);
    const int ci2 = lane * 128 + (int)(u2 & 0x7Fu);

    float bs = cs1;
    int bi = ci1;
    #pragma unroll
    for (int off = 32; off; off >>= 1) {
        const float os = __shfl_xor(bs, off);
        const int oi = __shfl_xor(bi, off);
        if (lexlt(os, oi, bs, bi)) { bs = os; bi = oi; }
    }

    const float tau = 0.25f;   // >> 2*(bf16 eps ~0.035) + key truncation 4e-3
    const unsigned long long m1 = __ballot(cs1 <= bs + tau);
    const unsigned long long m2 = __ballot(cs2 <= bs + tau);
    int winner = bi;

    if (__popcll(m1) + __popcll(m2) > 1) {
        const float4 z4 = *reinterpret_cast<const float4*>(
            z + (size_t)token * C + lane * 4);
        float best = 3.4e38f;
        int besti = 0x7fffffff;
        #pragma unroll 1
        for (int pass = 0; pass < 2; ++pass) {
            unsigned long long mm = pass ? m2 : m1;
            while (mm) {
                const int l = __builtin_ctzll(mm);
                mm &= mm - 1;
                const int cidx = __shfl(pass ? ci2 : ci1, l);
                const float4 e4 = *reinterpret_cast<const float4*>(
                    emb + (size_t)cidx * C + lane * 4);
                float p = 0.5f * (e4.x * e4.x + e4.y * e4.y + e4.z * e4.z +
                                  e4.w * e4.w)
                        - (z4.x * e4.x + z4.y * e4.y + z4.z * e4.z + z4.w * e4.w);
                #pragma unroll
                for (int off = 32; off; off >>= 1) p += __shfl_xor(p, off);
                if (lexlt(p, cidx, best, besti)) { best = p; besti = cidx; }
            }
        }
        winner = besti;
    }

    const float4 v = *reinterpret_cast<const float4*>(
        emb + (size_t)winner * C + lane * 4);
    *reinterpret_cast<float4*>(out + (size_t)token * C + lane * 4) = v;
}

extern "C" void kernel_launch(void* const* d_in, const int* in_sizes, int n_in,
                              void* d_out, int out_size, void* d_ws, size_t ws_size,
                              hipStream_t stream) {
    const float* z = (const float*)d_in[0];
    const float* emb = (const float*)d_in[1];
    float* out = (float*)d_out;

    char* w = (char*)d_ws;
    float* hn = (float*)w;            w += (size_t)NCODE * 4;
    ushort* zf = (ushort*)w;          w += (size_t)MTOK * C * 2;   // 8 MB
    ushort* eb = (ushort*)w;          w += (size_t)NCODE * C * 2;  // 4 MB
    float2* slab = (float2*)w;        // MTOK*NSLAB*8B = 16.8 MB

    vq_ecast<<<NCODE / 16, 256, 0, stream>>>(emb, eb, hn);
    vq_zfrag<<<MTOK * C / (8 * 256), 256, 0, stream>>>(z, zf);

    vq_gemm<<<dim3(MTOK / BM, NCODE / BN), TPB, 0, stream>>>(zf, eb, hn, slab);

    vq_pick<<<MTOK / 4, 256, 0, stream>>>(z, emb, slab, out);
}

// Round 21
// 99.452 us; speedup vs baseline: 1.2286x; 1.2286x over previous
//
#include <hip/hip_runtime.h>

// VQ nearest-codebook via bf16 MFMA GEMM + exact-fp32 rescue.
// score(n,k) = 0.5*|e_k|^2 - z_n.e_k (monotone in squared distance)
//
// Round-21: REVERT to round-18 (best measured: 99.7 us total). The 32x32
// MFMA branch is falsified both ways (r19: LDS bank conflicts; r20:
// uncoalesced fragment-ordered staging). r18's 16x16 structure with
// swapped-operand in-lane epilogue is the measured optimum: MfmaUtil 32%,
// VALUBusy 46% (~78% combined issue), conflicts 0, VGPR 60 (2 blk/CU).

typedef unsigned short ushort;
typedef unsigned int u32;
typedef __attribute__((ext_vector_type(8))) short short8;
typedef __attribute__((ext_vector_type(4))) float f32x4;

#define C 256
#define MTOK 16384
#define NCODE 8192
#define BM 256
#define BN 128
#define BK 64
#define TPB 512
#define NSLAB 128            // per-(nb,wc) entries, 64-code granularity
#define NTILE (C / BK)       // 4
// zf strides in ushort units: [mb][kk](16384)[h](8192)[wr](2048)[f](512)[lane](8)

__device__ __forceinline__ ushort bf16_rne(float x) {
    unsigned u = __float_as_uint(x);
    return (ushort)((u + 0x7FFFu + ((u >> 16) & 1u)) >> 16);
}

__device__ __forceinline__ bool lexlt(float as, int ai, float bs, int bi) {
    return as < bs || (as == bs && ai < bi);
}

// float sortable key: truncate score to 25 bits, OR in 7-bit local code id
// (id = cb | idc, bit-disjoint). Rescue pass restores exact semantics.
__device__ __forceinline__ float fkey(float sc, int id) {
    return __uint_as_float((__float_as_uint(sc) & 0xFFFFFF80u) | (u32)id);
}

__device__ __forceinline__ void ins2f(float& k1, float& k2, float key) {
    k2 = fminf(k2, fmaxf(k1, key));
    k1 = fminf(k1, key);
}

__device__ __forceinline__ void merge2f(float& k1, float& k2, float o1, float o2) {
    const float lo = fminf(k1, o1);
    const float hi = fmaxf(k1, o1);
    k2 = fminf(hi, fminf(k2, o2));
    k1 = lo;
}

__device__ __forceinline__ void gload_lds16(const ushort* g, ushort* l) {
    __builtin_amdgcn_global_load_lds(
        (const __attribute__((address_space(1))) unsigned int*)g,
        (__attribute__((address_space(3))) unsigned int*)l, 16, 0, 0);
}

// fused: emb -> bf16 cast + half-norms (one pass over emb)
__global__ __launch_bounds__(256) void vq_ecast(const float* __restrict__ emb,
                                                ushort* __restrict__ eb,
                                                float* __restrict__ hn) {
    typedef __attribute__((ext_vector_type(4))) ushort us4;
    const int lane = threadIdx.x & 63;
    const int wid = threadIdx.x >> 6;
    const int row0 = blockIdx.x * 16 + wid * 4;
    #pragma unroll
    for (int j = 0; j < 4; ++j) {
        const int k = row0 + j;
        const float4 v = *reinterpret_cast<const float4*>(
            emb + (size_t)k * C + lane * 4);
        us4 h;
        h[0] = bf16_rne(v.x);
        h[1] = bf16_rne(v.y);
        h[2] = bf16_rne(v.z);
        h[3] = bf16_rne(v.w);
        *reinterpret_cast<us4*>(eb + (size_t)k * C + lane * 4) = h;
        float s = v.x * v.x + v.y * v.y + v.z * v.z + v.w * v.w;
        #pragma unroll
        for (int off = 32; off; off >>= 1) s += __shfl_down(s, off);
        if (lane == 0) hn[k] = 0.5f * s;
    }
}

// z fp32 -> bf16 in MFMA fragment order (one 16B chunk per thread)
__global__ __launch_bounds__(256) void vq_zfrag(const float* __restrict__ z,
                                                ushort* __restrict__ zf) {
    typedef __attribute__((ext_vector_type(8))) ushort us8;
    const int c = blockIdx.x * 256 + threadIdx.x;   // chunk id, 524288 total
    const int r16 = c & 15;
    const int ag = (c >> 4) & 3;
    const int f  = (c >> 6) & 3;
    const int wr = (c >> 8) & 3;
    const int h  = (c >> 10) & 1;
    const int kk = (c >> 11) & 3;
    const int mb = c >> 13;
    const int row = mb * 256 + wr * 64 + f * 16 + r16;
    const int col = kk * 64 + h * 32 + ag * 8;
    const float4 v0 = *reinterpret_cast<const float4*>(z + (size_t)row * C + col);
    const float4 v1 = *reinterpret_cast<const float4*>(z + (size_t)row * C + col + 4);
    us8 o;
    o[0] = bf16_rne(v0.x); o[1] = bf16_rne(v0.y);
    o[2] = bf16_rne(v0.z); o[3] = bf16_rne(v0.w);
    o[4] = bf16_rne(v1.x); o[5] = bf16_rne(v1.y);
    o[6] = bf16_rne(v1.z); o[7] = bf16_rne(v1.w);
    *reinterpret_cast<us8*>(zf + (size_t)c * 8) = o;
}

__global__ __launch_bounds__(TPB) void vq_gemm(
    const ushort* __restrict__ zf, const ushort* __restrict__ eb,
    const float* __restrict__ hn, float2* __restrict__ slab) {
    __shared__ ushort smem[2 * BN * BK];   // 32 KB: B double-buffer

    const int tid = threadIdx.x;
    const int lane = tid & 63;
    const int wid = __builtin_amdgcn_readfirstlane(tid >> 6);
    const int wr = wid >> 1;          // 0..3 (M quarter, tokens)
    const int wc = wid & 1;           // 0..1 (N half, codes)
    const int mb = blockIdx.x;
    const int mbase = mb * BM;
    const int nb = blockIdx.y;
    const int nbase = nb * BN;

    // B staging: one issue = 512 thr x 16 B = 64 rows; wave covers 8 rows
    const int srow = wid * 8 + (lane >> 3);      // + i*64
    const int schunk = (lane & 7) ^ (lane >> 3); // pre-swizzled source chunk

    // z fragment base for this wave (ushort units)
    const ushort* zaw = zf + (size_t)mb * 4 * 16384 + wr * 2048 + lane * 8;

    f32x4 acc[4][4];
    #pragma unroll
    for (int a = 0; a < 4; ++a)
        #pragma unroll
        for (int b = 0; b < 4; ++b) acc[a][b] = (f32x4){0.f, 0.f, 0.f, 0.f};

    // prologue: stage e(0) into buf0
    #pragma unroll
    for (int i = 0; i < 2; ++i) {
        const int row = i * 64 + srow;
        gload_lds16(eb + (size_t)(nbase + row) * C + schunk * 8,
                    &smem[(i * 64 + wid * 8) * BK]);
    }
    __syncthreads();

    #pragma unroll 1
    for (int kk = 0; kk < NTILE; ++kk) {
        // z(kk) fragment loads (32 VGPR, same regs every iter)
        short8 a0[4], a1[4];
        const ushort* za = zaw + kk * 16384;
        #pragma unroll
        for (int f = 0; f < 4; ++f) {
            a0[f] = *reinterpret_cast<const short8*>(za + f * 512);
            a1[f] = *reinterpret_cast<const short8*>(za + 8192 + f * 512);
        }
        // stage e(kk+1) into the other buffer (flies during compute, 0 VGPR)
        if (kk + 1 < NTILE) {
            const int k0 = (kk + 1) * BK;
            ushort* Bn = &smem[((kk + 1) & 1) * BN * BK];
            #pragma unroll
            for (int i = 0; i < 2; ++i) {
                const int row = i * 64 + srow;
                gload_lds16(eb + (size_t)(nbase + row) * C + k0 + schunk * 8,
                            &Bn[(i * 64 + wid * 8) * BK]);
            }
        }

        const ushort* Bt = &smem[(kk & 1) * BN * BK];
        {   // h = 0
            short8 b[4];
            #pragma unroll
            for (int f = 0; f < 4; ++f) {
                const int br = wc * 64 + f * 16 + (lane & 15);
                const int ag = lane >> 4;
                b[f] = *reinterpret_cast<const short8*>(
                    &Bt[br * BK + ((ag ^ (br & 7)) * 8)]);
            }
            // swapped: A = e (codes), B = z (tokens) -> D[code][token]
            #pragma unroll
            for (int fi = 0; fi < 4; ++fi)
                #pragma unroll
                for (int fj = 0; fj < 4; ++fj)
                    acc[fi][fj] = __builtin_amdgcn_mfma_f32_16x16x32_bf16(
                        b[fi], a0[fj], acc[fi][fj], 0, 0, 0);
        }
        {   // h = 1
            short8 b[4];
            #pragma unroll
            for (int f = 0; f < 4; ++f) {
                const int br = wc * 64 + f * 16 + (lane & 15);
                const int ag = 4 + (lane >> 4);
                b[f] = *reinterpret_cast<const short8*>(
                    &Bt[br * BK + ((ag ^ (br & 7)) * 8)]);
            }
            #pragma unroll
            for (int fi = 0; fi < 4; ++fi)
                #pragma unroll
                for (int fj = 0; fj < 4; ++fj)
                    acc[fi][fj] = __builtin_amdgcn_mfma_f32_16x16x32_bf16(
                        b[fi], a1[fj], acc[fi][fj], 0, 0, 0);
        }
        __syncthreads();   // buf reads done + next e resident
    }

    // ---- epilogue: per-token (in-lane) top-2 over this wave's 64 codes ----
    // D: col = token = wr*64 + fj*16 + (lane&15)
    //    row = code = wc*64 + fi*16 + (lane>>4)*4 + r
    const int cb = wc * 64 + (lane >> 4) * 4;   // lane's local-code base
    float4 hv4[4];                               // loaded post-loop: a0/a1 dead
    #pragma unroll
    for (int fi = 0; fi < 4; ++fi)
        hv4[fi] = *reinterpret_cast<const float4*>(&hn[nbase + cb + fi * 16]);

    #pragma unroll
    for (int fj = 0; fj < 4; ++fj) {
        float k1 = 3.4e38f, k2 = 3.4e38f;
        #pragma unroll
        for (int fi = 0; fi < 4; ++fi) {
            ins2f(k1, k2, fkey(hv4[fi].x - acc[fi][fj][0], cb | (fi * 16 + 0)));
            ins2f(k1, k2, fkey(hv4[fi].y - acc[fi][fj][1], cb | (fi * 16 + 1)));
            ins2f(k1, k2, fkey(hv4[fi].z - acc[fi][fj][2], cb | (fi * 16 + 2)));
            ins2f(k1, k2, fkey(hv4[fi].w - acc[fi][fj][3], cb | (fi * 16 + 3)));
        }
        merge2f(k1, k2, __shfl_xor(k1, 16), __shfl_xor(k2, 16));
        merge2f(k1, k2, __shfl_xor(k1, 32), __shfl_xor(k2, 32));
        if (lane < 16) {
            const int token = mbase + wr * 64 + fj * 16 + lane;
            slab[(size_t)token * NSLAB + nb * 2 + wc] = make_float2(k1, k2);
        }
    }
}

__global__ __launch_bounds__(256) void vq_pick(
    const float* __restrict__ z, const float* __restrict__ emb,
    const float2* __restrict__ slab, float* __restrict__ out) {
    const int token = blockIdx.x * 4 + (threadIdx.x >> 6);
    const int lane = threadIdx.x & 63;

    // two entries per lane, same nbase (nb = lane) -> key-level merge valid
    const float2 e0 = slab[(size_t)token * NSLAB + 2 * lane];
    const float2 e1 = slab[(size_t)token * NSLAB + 2 * lane + 1];
    float k1 = e0.x, k2 = e0.y;
    merge2f(k1, k2, e1.x, e1.y);
    const u32 u1 = __float_as_uint(k1);
    const u32 u2 = __float_as_uint(k2);
    const float cs1 = __uint_as_float(u1 & 0xFFFFFF80u);
    const float cs2 = __uint_as_float(u2 & 0xFFFFFF80u);
    const int ci1 = lane * 128 + (int)(u1 & 0x7Fu);
    const int ci2 = lane * 128 + (int)(u2 & 0x7Fu);

    float bs = cs1;
    int bi = ci1;
    #pragma unroll
    for (int off = 32; off; off >>= 1) {
        const float os = __shfl_xor(bs, off);
        const int oi = __shfl_xor(bi, off);
        if (lexlt(os, oi, bs, bi)) { bs = os; bi = oi; }
    }

    const float tau = 0.25f;   // >> 2*(bf16 eps ~0.035) + key truncation 4e-3
    const unsigned long long m1 = __ballot(cs1 <= bs + tau);
    const unsigned long long m2 = __ballot(cs2 <= bs + tau);
    int winner = bi;

    if (__popcll(m1) + __popcll(m2) > 1) {
        const float4 z4 = *reinterpret_cast<const float4*>(
            z + (size_t)token * C + lane * 4);
        float best = 3.4e38f;
        int besti = 0x7fffffff;
        #pragma unroll 1
        for (int pass = 0; pass < 2; ++pass) {
            unsigned long long mm = pass ? m2 : m1;
            while (mm) {
                const int l = __builtin_ctzll(mm);
                mm &= mm - 1;
                const int cidx = __shfl(pass ? ci2 : ci1, l);
                const float4 e4 = *reinterpret_cast<const float4*>(
                    emb + (size_t)cidx * C + lane * 4);
                float p = 0.5f * (e4.x * e4.x + e4.y * e4.y + e4.z * e4.z +
                                  e4.w * e4.w)
                        - (z4.x * e4.x + z4.y * e4.y + z4.z * e4.z + z4.w * e4.w);
                #pragma unroll
                for (int off = 32; off; off >>= 1) p += __shfl_xor(p, off);
                if (lexlt(p, cidx, best, besti)) { best = p; besti = cidx; }
            }
        }
        winner = besti;
    }

    const float4 v = *reinterpret_cast<const float4*>(
        emb + (size_t)winner * C + lane * 4);
    *reinterpret_cast<float4*>(out + (size_t)token * C + lane * 4) = v;
}

extern "C" void kernel_launch(void* const* d_in, const int* in_sizes, int n_in,
                              void* d_out, int out_size, void* d_ws, size_t ws_size,
                              hipStream_t stream) {
    const float* z = (const float*)d_in[0];
    const float* emb = (const float*)d_in[1];
    float* out = (float*)d_out;

    char* w = (char*)d_ws;
    float* hn = (float*)w;            w += (size_t)NCODE * 4;
    ushort* zf = (ushort*)w;          w += (size_t)MTOK * C * 2;   // 8 MB
    ushort* eb = (ushort*)w;          w += (size_t)NCODE * C * 2;  // 4 MB
    float2* slab = (float2*)w;        // MTOK*NSLAB*8B = 16.8 MB

    vq_ecast<<<NCODE / 16, 256, 0, stream>>>(emb, eb, hn);
    vq_zfrag<<<MTOK * C / (8 * 256), 256, 0, stream>>>(z, zf);

    vq_gemm<<<dim3(MTOK / BM, NCODE / BN), TPB, 0, stream>>>(zf, eb, hn, slab);

    vq_pick<<<MTOK / 4, 256, 0, stream>>>(z, emb, slab, out);
}